// Round 1
// 268.054 us; speedup vs baseline: 1.0007x; 1.0007x over previous
//
#include <hip/hip_runtime.h>
#include <math.h>

#define N_NODES 100000
#define N_EDGES 1600000
#define EPS_    1e-5f
#define PAD     64          // ELL row capacity; P(Poisson(16) > 64) ~ 1e-20

// R9: XCD-partitioned ELL build. 8 sibling blocks share each 2048-edge chunk;
// sibling p owns dst range [p*12500, (p+1)*12500). With round-robin blockIdx->XCD
// dispatch (part = blockIdx & 7), each ell/cnt line is written through exactly one
// XCD L2 -> the ~16 stores per 64B ell line merge into ~1 writeback instead of ~16
// cross-XCD ping-pong writebacks (rocprof R8: WRITE_SIZE 121MB ~= 64B per 4B store).
#define EDGES_PER_BLK 2048
#define NCHUNK  782                  // ceil(E / 2048)
#define NB_BUILD (NCHUNK * 8)        // 6256 blocks
#define NWAVES_L (NB_BUILD * 4)
#define PART_SZ  12500               // N_NODES / 8

// ---- bf16 helpers (raw ushort storage, RNE on pack) -----------------------
__device__ __forceinline__ float bf2f(unsigned short u) {
    union { unsigned int i; float f; } v; v.i = (unsigned int)u << 16; return v.f;
}
__device__ __forceinline__ unsigned short f2bf(float f) {
    union { float f; unsigned int i; } v; v.f = f;
    unsigned int b = v.i + 0x7FFFu + ((v.i >> 16) & 1u);   // round-to-nearest-even
    return (unsigned short)(b >> 16);
}

// ---------------------------------------------------------------------------
// Kernel 1: merged ELL build + lin. Phase A: block (chunk,part) scans 2048
// edges (int4 bulk reads, 8/thread) and issues atomic+store only for dsts in
// its partition -> single-L2 write locality. Phase B: same lin chunk as R8 —
// pure VALU/LDS work executing in the atomic/store drain's shadow. hg stored
// UNSCALED (no dependence on final cnt).
// ---------------------------------------------------------------------------
__global__ void build_lin_kernel(const int* __restrict__ src,
                                 const int* __restrict__ dst,
                                 const float* __restrict__ x,
                                 const float* __restrict__ W1,
                                 const float* __restrict__ b1,
                                 const float* __restrict__ Wg,
                                 int* __restrict__ cnt,
                                 int* __restrict__ ell,
                                 unsigned short* __restrict__ hb_h,
                                 unsigned short* __restrict__ hb_g)
{
    __shared__ float sWg[64 * 64];
    const int tl    = threadIdx.x;
    const int part  = blockIdx.x & 7;          // aligns with round-robin XCD dispatch
    const int chunk = blockIdx.x >> 3;
    const int lo    = part * PART_SZ;
    const int hi    = lo + PART_SZ;

    // ---- Phase A: scan chunk, claim owned edges --------------------------
    const int ebase = chunk * EDGES_PER_BLK + tl * 8;
    int dv[8], sv[8];
    if (ebase + 8 <= N_EDGES) {
        const int4 d0 = *(const int4*)(dst + ebase);
        const int4 d1 = *(const int4*)(dst + ebase + 4);
        const int4 s0 = *(const int4*)(src + ebase);
        const int4 s1 = *(const int4*)(src + ebase + 4);
        dv[0] = d0.x; dv[1] = d0.y; dv[2] = d0.z; dv[3] = d0.w;
        dv[4] = d1.x; dv[5] = d1.y; dv[6] = d1.z; dv[7] = d1.w;
        sv[0] = s0.x; sv[1] = s0.y; sv[2] = s0.z; sv[3] = s0.w;
        sv[4] = s1.x; sv[5] = s1.y; sv[6] = s1.z; sv[7] = s1.w;
    } else {
#pragma unroll
        for (int j = 0; j < 8; ++j) {
            const int e = ebase + j;
            if (e < N_EDGES) { dv[j] = dst[e]; sv[j] = src[e]; }
            else             { dv[j] = -1;     sv[j] = 0;      }
        }
    }

    int pos[8];
#pragma unroll
    for (int j = 0; j < 8; ++j) {
        pos[j] = -1;
        if (dv[j] >= lo && dv[j] < hi) pos[j] = atomicAdd(&cnt[dv[j]], 1);
    }

    // Stage Wg -> LDS while the atomics are in flight (independent work).
    for (int i = tl; i < 64 * 64; i += 256) sWg[i] = Wg[i];

#pragma unroll
    for (int j = 0; j < 8; ++j)
        if (pos[j] >= 0 && pos[j] < PAD) ell[dv[j] * PAD + pos[j]] = sv[j];
    __syncthreads();

    // ---- Phase B: lin chunk (VALU-bound, hides under atomic drain) -------
    const int lane  = tl & 63;
    const int gwave = blockIdx.x * 4 + (tl >> 6);
    for (int n = gwave; n < N_NODES; n += NWAVES_L) {
        const float x0 = x[n * 3 + 0];
        const float x1 = x[n * 3 + 1];
        const float x2 = x[n * 3 + 2];
        float h = x0 * W1[lane] + x1 * W1[64 + lane] + x2 * W1[128 + lane] + b1[lane];
        h = fmaxf(h, 0.0f);

        float acc = 0.0f;
#pragma unroll 16
        for (int k = 0; k < 64; ++k) {
            const float hk = __shfl(h, k, 64);
            acc = fmaf(hk, sWg[k * 64 + lane], acc);
        }
        hb_h[n * 64 + lane] = f2bf(h);
        hb_g[n * 64 + lane] = f2bf(acc);          // unscaled — cnt not final yet
    }
}

// ---------------------------------------------------------------------------
// Kernel 2: hb_g[n][c] *= rsqrt(cnt[n]+1)  (in place, dword grain, ~6 us)
// ---------------------------------------------------------------------------
__global__ void scale_kernel(const int* __restrict__ cnt,
                             unsigned int* __restrict__ g2)
{
    const int t = blockIdx.x * blockDim.x + threadIdx.x;
    if (t >= N_NODES * 32) return;
    const int node = t >> 5;
    const float di = rsqrtf((float)(cnt[node] + 1));
    const unsigned int v = g2[t];
    const float lo = bf2f((unsigned short)(v & 0xFFFFu)) * di;
    const float hi = bf2f((unsigned short)(v >> 16)) * di;
    g2[t] = (unsigned int)f2bf(lo) | ((unsigned int)f2bf(hi) << 16);
}

// ---------------------------------------------------------------------------
// Kernel 3: gather + epilogue. One wave per dst node, lane = channel.
//   acc = hgs[n] (self) + sum over ELL row hgs[src]   (dinv[src] pre-folded)
//   h2  = relu(dinv[n]*acc + bg);  out = LayerNorm128([h,h2])*gamma + beta
// ---------------------------------------------------------------------------
__global__ void gather_final_kernel(const unsigned short* __restrict__ hb_h,
                                    const unsigned short* __restrict__ hb_g,
                                    const int* __restrict__ cnt,
                                    const int* __restrict__ ell,
                                    const float* __restrict__ bg,
                                    const float* __restrict__ gamma,
                                    const float* __restrict__ beta,
                                    float* __restrict__ out)
{
    const int lane = threadIdx.x & 63;
    const int n    = blockIdx.x * (blockDim.x >> 6) + (threadIdx.x >> 6);
    if (n >= N_NODES) return;

    const int c    = cnt[n];
    const float di = rsqrtf((float)(c + 1));
    const int deg  = (c < PAD) ? c : PAD;
    const int* __restrict__ row = ell + n * PAD;

    const float h = bf2f(hb_h[n * 64 + lane]);       // issue early
    float acc = bf2f(hb_g[n * 64 + lane]);           // self loop (scaled)

    int j = 0;
    for (; j + 8 <= deg; j += 8) {                   // 8 gathers in flight
        const int4 r0 = *(const int4*)(row + j);
        const int4 r1 = *(const int4*)(row + j + 4);
        const float a0 = bf2f(hb_g[r0.x * 64 + lane]);
        const float a1 = bf2f(hb_g[r0.y * 64 + lane]);
        const float a2 = bf2f(hb_g[r0.z * 64 + lane]);
        const float a3 = bf2f(hb_g[r0.w * 64 + lane]);
        const float a4 = bf2f(hb_g[r1.x * 64 + lane]);
        const float a5 = bf2f(hb_g[r1.y * 64 + lane]);
        const float a6 = bf2f(hb_g[r1.z * 64 + lane]);
        const float a7 = bf2f(hb_g[r1.w * 64 + lane]);
        acc += ((a0 + a1) + (a2 + a3)) + ((a4 + a5) + (a6 + a7));
    }
    if (j + 4 <= deg) {
        const int4 r0 = *(const int4*)(row + j);
        acc += (bf2f(hb_g[r0.x * 64 + lane]) + bf2f(hb_g[r0.y * 64 + lane]))
             + (bf2f(hb_g[r0.z * 64 + lane]) + bf2f(hb_g[r0.w * 64 + lane]));
        j += 4;
    }
    for (; j < deg; ++j) acc += bf2f(hb_g[row[j] * 64 + lane]);

    float h2 = fmaxf(fmaf(di, acc, bg[lane]), 0.0f);

    float sum = h + h2;
#pragma unroll
    for (int o = 32; o > 0; o >>= 1) sum += __shfl_xor(sum, o, 64);
    const float mu = sum * (1.0f / 128.0f);

    const float d0 = h - mu;
    const float d1 = h2 - mu;
    float vs = d0 * d0 + d1 * d1;
#pragma unroll
    for (int o = 32; o > 0; o >>= 1) vs += __shfl_xor(vs, o, 64);
    const float r = rsqrtf(vs * (1.0f / 128.0f) + EPS_);

    out[n * 128 + lane]      = d0 * r * gamma[lane]      + beta[lane];
    out[n * 128 + 64 + lane] = d1 * r * gamma[64 + lane] + beta[64 + lane];
}

// ---------------------------------------------------------------------------
extern "C" void kernel_launch(void* const* d_in, const int* in_sizes, int n_in,
                              void* d_out, int out_size, void* d_ws, size_t ws_size,
                              hipStream_t stream)
{
    const float* x     = (const float*)d_in[0];
    const int*   edge  = (const int*)  d_in[1];   // [2, E]: row0 = src, row1 = dst
    const float* W1    = (const float*)d_in[2];
    const float* b1    = (const float*)d_in[3];
    const float* Wg    = (const float*)d_in[4];
    const float* bg    = (const float*)d_in[5];
    const float* gamma = (const float*)d_in[6];
    const float* beta  = (const float*)d_in[7];
    float*       out   = (float*)d_out;

    // Workspace layout (~51.6 MB): hb_g | hb_h | ell | cnt  (16B-aligned)
    char*  ws  = (char*)d_ws;
    size_t p   = 0;
    unsigned short* hb_g = (unsigned short*)(ws + p); p += (size_t)N_NODES * 64 * sizeof(unsigned short);
    unsigned short* hb_h = (unsigned short*)(ws + p); p += (size_t)N_NODES * 64 * sizeof(unsigned short);
    int*            ell  = (int*)           (ws + p); p += (size_t)N_NODES * PAD * sizeof(int);
    int*            cnt  = (int*)           (ws + p);

    const int* src = edge;
    const int* dst = edge + N_EDGES;

    hipMemsetAsync(cnt, 0, (size_t)N_NODES * sizeof(int), stream);

    build_lin_kernel<<<NB_BUILD, 256, 0, stream>>>(src, dst, x, W1, b1, Wg,
                                                   cnt, ell, hb_h, hb_g);
    scale_kernel<<<(N_NODES * 32 + 255) / 256, 256, 0, stream>>>(cnt, (unsigned int*)hb_g);
    gather_final_kernel<<<(N_NODES + 3) / 4, 256, 0, stream>>>(hb_h, hb_g, cnt, ell,
                                                               bg, gamma, beta, out);
}